// Round 9
// baseline (416.186 us; speedup 1.0000x reference)
//
#include <hip/hip_runtime.h>
#include <hip/hip_fp16.h>
#include <math.h>

#define NN 40000
#define EE 500000
#define CC 128
#define GG 800
#define FINN 56
#define NEGS 0.2f
#define CAP 48

typedef _Float16 f16x8 __attribute__((ext_vector_type(8)));
typedef float f32x4 __attribute__((ext_vector_type(4)));

__device__ __forceinline__ float lrelu(float x) { return x > 0.f ? x : NEGS * x; }

// ---------------- prep: zero deg, Wt/Wet fp16 transposes, wedot ----------------
#define WGSZ (3 * 256 * 128)
#define WESZ (128 * 64)
#define PREPN ((WGSZ + WESZ) / 256)   // 416 full blocks; block 416 = wedot

__global__ void k_prep(const float* __restrict__ Wg, const float* __restrict__ W_emb,
                       const float* __restrict__ We, const float* __restrict__ ate,
                       __half* __restrict__ Wt, __half* __restrict__ Wet,
                       float* __restrict__ wd, int* __restrict__ deg) {
    int gi = blockIdx.x * 256 + threadIdx.x;
    if (gi < NN) deg[gi] = 0;
    if (blockIdx.x == PREPN) {
        if (threadIdx.x < 64) {
            int lane = threadIdx.x;
            for (int idx = 0; idx < 6; ++idx) {
                const float* w = We + idx * 128;
                const float* a = ate + idx * 128;
                float p = w[lane] * a[lane] + w[lane + 64] * a[lane + 64];
                #pragma unroll
                for (int m = 32; m; m >>= 1) p += __shfl_xor(p, m);
                if (lane == 0) wd[idx] = p;
            }
        }
        return;
    }
    if (gi < WGSZ) {                      // Wt[l][c][k] = Wg[l][k][c]
        int l = gi >> 15, rem = gi & 32767;
        int c = rem >> 7, kk = rem & 127;
        Wt[gi] = __float2half_rn(Wg[l * 32768 + kk * 256 + c]);
    } else {                              // Wet[c][k] = W_emb[k][c], K padded to 64
        int j = gi - WGSZ;
        int c = j >> 6, kk = j & 63;
        Wet[j] = (kk < FINN) ? __float2half_rn(W_emb[kk * CC + c]) : __half(0.f);
    }
}

// ---------------- slab CSR scatter: csr[d*CAP + slot] ----------------
__global__ void k_scatter(const int* __restrict__ ei, const float* __restrict__ ea,
                          const float* __restrict__ mu, const float* __restrict__ dev,
                          int* __restrict__ deg, int4* __restrict__ slab) {
    int e = blockIdx.x * 256 + threadIdx.x;
    if (e >= EE) return;
    int s = ei[e], d = ei[EE + e];
    float a1 = ea[2 * e];
    float xx = ea[2 * e + 1] - mu[0];
    float a2 = __expf(-xx * xx / dev[0]) + a1;
    int p = atomicAdd(&deg[d], 1);
    if (p < CAP) slab[d * CAP + p] = make_int4(s, __float_as_int(a1), __float_as_int(a2), 0);
}

// ---------------- embed via MFMA: h = x @ Wet^T (K=64), LDS-staged h16 store ----------------
__global__ __launch_bounds__(128) void k_embed16(
    const float* __restrict__ x, const __half* __restrict__ Wet,
    float* __restrict__ h, __half* __restrict__ h16) {
    __shared__ __half tile[16][136];   // 128 cols + 8 pad (row stride 272B, 16B aligned)
    int tid = threadIdx.x;
    int wave = tid >> 6, lane = tid & 63;
    int row0 = blockIdx.x * 16;
    int rlo = lane & 15, kgrp = lane >> 4;
    const float* xrow = x + (row0 + rlo) * FINN;
    f16x8 a0, a1;
    #pragma unroll
    for (int j = 0; j < 8; ++j) a0[j] = (_Float16)xrow[kgrp * 8 + j];
    #pragma unroll
    for (int j = 0; j < 8; ++j) {
        int k = 32 + kgrp * 8 + j;
        a1[j] = (k < FINN) ? (_Float16)xrow[k] : (_Float16)0.f;
    }
    #pragma unroll
    for (int nt = 0; nt < 4; ++nt) {
        int col = wave * 64 + nt * 16 + rlo;
        f32x4 acc = {0.f, 0.f, 0.f, 0.f};
        const __half* bbase = Wet + col * 64 + kgrp * 8;
        acc = __builtin_amdgcn_mfma_f32_16x16x32_f16(a0, *(const f16x8*)(bbase), acc, 0, 0, 0);
        acc = __builtin_amdgcn_mfma_f32_16x16x32_f16(a1, *(const f16x8*)(bbase + 32), acc, 0, 0, 0);
        #pragma unroll
        for (int r = 0; r < 4; ++r) {
            int row = row0 + kgrp * 4 + r;
            h[row * CC + col] = acc[r];
            tile[kgrp * 4 + r][col] = __float2half_rn(acc[r]);
        }
    }
    __syncthreads();
    int row = tid >> 3, chunk = tid & 7;           // 16 rows x 8 chunks of 16 halfs
    uint4 a = *(uint4*)&tile[row][chunk * 16];
    uint4 b = *(uint4*)&tile[row][chunk * 16 + 8];
    __half* dst = &h16[(row0 + row) * CC + chunk * 16];
    *(uint4*)dst = a;
    *(uint4*)(dst + 8) = b;
}

// ---------------- MFMA GEMM: hh16 = h16 @ Wt^T, fused ls/ld, LDS-staged stores ----------------
__global__ __launch_bounds__(256) void k_gemm16(
    const __half* __restrict__ h16, const __half* __restrict__ Wt,
    const float* __restrict__ as_, const float* __restrict__ ad_,
    __half* __restrict__ hh16, float* __restrict__ lsld) {
    __shared__ __half tile[16][264];   // 256 cols + 8 pad (row stride 528B, 16B aligned)
    __shared__ float2 red[16][4];
    int tid = threadIdx.x;
    int wave = tid >> 6, lane = tid & 63;
    int row0 = blockIdx.x * 16;
    int rlo = lane & 15, kgrp = lane >> 4;
    f16x8 afrag[4];
    const __half* abase = h16 + (row0 + rlo) * CC + kgrp * 8;
    #pragma unroll
    for (int ks = 0; ks < 4; ++ks) afrag[ks] = *(const f16x8*)(abase + ks * 32);
    int head = wave >> 1;
    const float* as_h = as_ + head * CC;
    const float* ad_h = ad_ + head * CC;
    float psum[4] = {0.f, 0.f, 0.f, 0.f}, pdsum[4] = {0.f, 0.f, 0.f, 0.f};
    #pragma unroll
    for (int nt = 0; nt < 4; ++nt) {
        int col = wave * 64 + nt * 16 + rlo;
        f32x4 acc = {0.f, 0.f, 0.f, 0.f};
        const __half* bbase = Wt + col * CC + kgrp * 8;
        #pragma unroll
        for (int ks = 0; ks < 4; ++ks) {
            f16x8 bfrag = *(const f16x8*)(bbase + ks * 32);
            acc = __builtin_amdgcn_mfma_f32_16x16x32_f16(afrag[ks], bfrag, acc, 0, 0, 0);
        }
        float av = as_h[col & 127], dv = ad_h[col & 127];
        #pragma unroll
        for (int r = 0; r < 4; ++r) {
            float v = acc[r];
            tile[kgrp * 4 + r][col] = __float2half_rn(v);
            psum[r] += v * av;
            pdsum[r] += v * dv;
        }
    }
    #pragma unroll
    for (int r = 0; r < 4; ++r) {
        #pragma unroll
        for (int m = 1; m < 16; m <<= 1) {
            psum[r] += __shfl_xor(psum[r], m);
            pdsum[r] += __shfl_xor(pdsum[r], m);
        }
    }
    if (rlo == 0) {
        #pragma unroll
        for (int r = 0; r < 4; ++r) red[kgrp * 4 + r][wave] = make_float2(psum[r], pdsum[r]);
    }
    __syncthreads();
    {   // vectorized hh16 store: 16 rows x 16 chunks of 16 halfs (32B per thread)
        int row = tid >> 4, chunk = tid & 15;
        uint4 a = *(uint4*)&tile[row][chunk * 16];
        uint4 b = *(uint4*)&tile[row][chunk * 16 + 8];
        __half* dst = &hh16[(row0 + row) * 256 + chunk * 16];
        *(uint4*)dst = a;
        *(uint4*)(dst + 8) = b;
    }
    if (tid < 64) {
        int row = tid >> 2, which = tid & 3;
        float v;
        if (which == 0)      v = red[row][0].x + red[row][1].x;  // ls0
        else if (which == 1) v = red[row][2].x + red[row][3].x;  // ls1
        else if (which == 2) v = red[row][0].y + red[row][1].y;  // ld0
        else                 v = red[row][2].y + red[row][3].y;  // ld1
        lsld[(row0 + row) * 4 + which] = v;
    }
}

// ---------------- fused attention: one node per half-wave, 2-wide PV ----------------
__global__ __launch_bounds__(256) void k_attn(
    const __half* __restrict__ hh16, const float* __restrict__ hcur,
    const float* __restrict__ lsld,
    const int* __restrict__ deg, const int4* __restrict__ slab,
    const float* __restrict__ wd, const float* __restrict__ bg,
    const float* __restrict__ gw, const float* __restrict__ gb,
    float* __restrict__ hout, __half* __restrict__ h16out) {
    __shared__ float4 evM[8][32];
    __shared__ int    evS[8][32];
    int tid = threadIdx.x;
    int sub = tid & 31;
    int hw = tid >> 5;
    int n = blockIdx.x * 8 + hw;      // NN % 8 == 0
    float wd0 = wd[0], wd1 = wd[1];
    float4 nld = *(const float4*)&lsld[n * 4];
    float ld0 = nld.z, ld1 = nld.w;
    int count = min(deg[n], CAP);
    const int4* srow = slab + n * CAP;
    int hd01 = sub >> 4;
    float s0 = 0, s1 = 0, s2 = 0, s3 = 0;
    float acc1[8] = {0,0,0,0,0,0,0,0}, acc2[8] = {0,0,0,0,0,0,0,0};
    const char* hbase = (const char*)hh16 + sub * 16;

    for (int j0 = 0; j0 < count; j0 += 32) {
        int nact = min(32, count - j0);
        float4 e4 = make_float4(0.f, 0.f, 0.f, 0.f);
        int smine = 0;
        if (j0 + sub < count) {
            int4 c = srow[j0 + sub];
            smine = c.x;
            float a1 = __int_as_float(c.y), a2 = __int_as_float(c.z);
            float2 lsv = *(const float2*)&lsld[smine * 4];
            float b0 = lsv.x + ld0, b1 = lsv.y + ld1;
            e4.x = __expf(fminf(lrelu(b0 + a1 * wd0), 80.f));
            e4.y = __expf(fminf(lrelu(b0 + a2 * wd0), 80.f));
            e4.z = __expf(fminf(lrelu(b1 + a1 * wd1), 80.f));
            e4.w = __expf(fminf(lrelu(b1 + a2 * wd1), 80.f));
            s0 += e4.x; s1 += e4.y; s2 += e4.z; s3 += e4.w;
        }
        evM[hw][sub] = e4;                 // zero-padded beyond nact
        evS[hw][sub] = smine * 512;
        int npv = (nact + 1) & ~1;         // 2-wide, zero-padded -> no guards
        for (int jj = 0; jj < npv; jj += 2) {
            float4 emA = evM[hw][jj], emB = evM[hw][jj + 1];
            int oA = evS[hw][jj], oB = evS[hw][jj + 1];
            union { uint4 u; _Float16 hx[8]; } rA, rB;
            rA.u = *(const uint4*)(hbase + oA);
            rB.u = *(const uint4*)(hbase + oB);
            float eA1 = hd01 ? emA.z : emA.x, eA2 = hd01 ? emA.w : emA.y;
            float eB1 = hd01 ? emB.z : emB.x, eB2 = hd01 ? emB.w : emB.y;
            #pragma unroll
            for (int i = 0; i < 8; ++i) {
                float vA = (float)rA.hx[i], vB = (float)rB.hx[i];
                acc1[i] += eA1 * vA; acc2[i] += eA2 * vA;
                acc1[i] += eB1 * vB; acc2[i] += eB2 * vB;
            }
        }
    }
    #pragma unroll
    for (int m = 16; m; m >>= 1) {
        s0 += __shfl_xor(s0, m); s1 += __shfl_xor(s1, m);
        s2 += __shfl_xor(s2, m); s3 += __shfl_xor(s3, m);
    }
    float d1 = (hd01 ? s2 : s0) + 1e-16f;
    float d2 = (hd01 ? s3 : s1) + 1e-16f;
    float id1 = 1.f / d1, id2 = 1.f / d2;
    int c0 = (sub & 15) * 8;
    float o1[8], o2[8];
    #pragma unroll
    for (int i = 0; i < 8; ++i) { o1[i] = acc1[i] * id1; o2[i] = acc2[i] * id2; }
    #pragma unroll
    for (int i = 0; i < 8; ++i) {
        o1[i] = 0.5f * (o1[i] + __shfl_xor(o1[i], 16)) + bg[c0 + i];
        o2[i] = 0.5f * (o2[i] + __shfl_xor(o2[i], 16)) + bg[c0 + i];
    }
    float hv[8];
    *(float4*)&hv[0] = ((const float4*)hcur)[n * 32 + (sub & 15) * 2];
    *(float4*)&hv[4] = ((const float4*)hcur)[n * 32 + (sub & 15) * 2 + 1];
    float pp1 = 0.f, pp2 = 0.f;
    if (sub < 16) {
        #pragma unroll
        for (int i = 0; i < 8; ++i) {
            pp1 += o1[i] * gw[128 + c0 + i];
            pp2 += o2[i] * gw[128 + c0 + i];
        }
    } else {
        float hp = 0.f;
        #pragma unroll
        for (int i = 0; i < 8; ++i) hp += hv[i] * gw[c0 + i];
        pp1 = hp; pp2 = hp;
    }
    #pragma unroll
    for (int m = 16; m; m >>= 1) { pp1 += __shfl_xor(pp1, m); pp2 += __shfl_xor(pp2, m); }
    float z1 = 1.f / (1.f + __expf(-(pp1 + gb[0])));
    float z2 = 1.f / (1.f + __expf(-(pp2 + gb[0])));
    if (sub < 16) {
        float r[8];
        #pragma unroll
        for (int i = 0; i < 8; ++i) {
            float g1 = z1 * hv[i] + (1.f - z1) * fmaxf(o1[i], 0.f);
            float g2 = z2 * hv[i] + (1.f - z2) * fmaxf(o2[i], 0.f);
            r[i] = g2 - g1;
        }
        ((float4*)hout)[n * 32 + (sub & 15) * 2]     = make_float4(r[0], r[1], r[2], r[3]);
        ((float4*)hout)[n * 32 + (sub & 15) * 2 + 1] = make_float4(r[4], r[5], r[6], r[7]);
        union { __half h[8]; uint4 u; } pk;
        #pragma unroll
        for (int i = 0; i < 8; ++i) pk.h[i] = __float2half_rn(r[i]);
        *(uint4*)&h16out[n * CC + c0] = pk.u;
    }
}

// ---------------- fused readout + MLP ----------------
__global__ __launch_bounds__(128) void k_readmlp(
    const float* __restrict__ h, const float* __restrict__ valid, const int* __restrict__ batch,
    const float* __restrict__ w0, const float* __restrict__ b0,
    const float* __restrict__ w1, const float* __restrict__ b1,
    const float* __restrict__ w2, const float* __restrict__ b2,
    const float* __restrict__ w3, const float* __restrict__ b3,
    float* __restrict__ out) {
    __shared__ float cur[256];
    __shared__ float nxt[128];
    int g = blockIdx.x, t = threadIdx.x;
    int lo = 0, hi = NN;
    while (lo < hi) { int mid = (lo + hi) >> 1; if (batch[mid] < g) lo = mid + 1; else hi = mid; }
    int s = lo;
    lo = s; hi = NN;
    while (lo < hi) { int mid = (lo + hi) >> 1; if (batch[mid] < g + 1) lo = mid + 1; else hi = mid; }
    int e = lo;
    float gl = 0, gp = 0;
    for (int n = s; n < e; ++n) {
        float hv = h[n * CC + t];
        gl += hv * valid[2 * n];
        gp += hv * valid[2 * n + 1];
    }
    cur[t] = gl; cur[t + 128] = gp;
    __syncthreads();
    float ss = b0[t];
    for (int i = 0; i < 256; ++i) ss += cur[i] * w0[i * 128 + t];
    nxt[t] = fmaxf(ss, 0.f);
    __syncthreads();
    ss = b1[t];
    for (int i = 0; i < 128; ++i) ss += nxt[i] * w1[i * 128 + t];
    cur[t] = fmaxf(ss, 0.f);
    __syncthreads();
    ss = b2[t];
    for (int i = 0; i < 128; ++i) ss += cur[i] * w2[i * 128 + t];
    nxt[t] = fmaxf(ss, 0.f);
    __syncthreads();
    if (t < 2) {
        float o = b3[t];
        for (int i = 0; i < 128; ++i) o += nxt[i] * w3[i * 2 + t];
        out[g * 2 + t] = (t == 1) ? expf(o) : o;
    }
}

extern "C" void kernel_launch(void* const* d_in, const int* in_sizes, int n_in,
                              void* d_out, int out_size, void* d_ws, size_t ws_size,
                              hipStream_t stream) {
    const float* x      = (const float*)d_in[0];
    const int*   ei     = (const int*)d_in[1];
    const float* ea     = (const float*)d_in[2];
    const float* valid  = (const float*)d_in[3];
    const int*   batch  = (const int*)d_in[4];
    const float* mu     = (const float*)d_in[5];
    const float* devp   = (const float*)d_in[6];
    const float* W_emb  = (const float*)d_in[7];
    const float* Wg     = (const float*)d_in[8];
    const float* att_s  = (const float*)d_in[9];
    const float* att_d  = (const float*)d_in[10];
    const float* We     = (const float*)d_in[11];
    const float* att_e  = (const float*)d_in[12];
    const float* bg     = (const float*)d_in[13];
    const float* gw     = (const float*)d_in[14];
    const float* gb     = (const float*)d_in[15];
    const float* fw0    = (const float*)d_in[16];
    const float* fb0    = (const float*)d_in[17];
    const float* fw1    = (const float*)d_in[18];
    const float* fb1    = (const float*)d_in[19];
    const float* fw2    = (const float*)d_in[20];
    const float* fb2    = (const float*)d_in[21];
    const float* fw3    = (const float*)d_in[22];
    const float* fb3    = (const float*)d_in[23];
    float* out = (float*)d_out;

    char* p = (char*)d_ws;
    auto alloc = [&](size_t bytes) -> char* {
        char* r = p;
        p += (bytes + 255) & ~(size_t)255;
        return r;
    };
    float*  h0      = (float*)alloc((size_t)NN * CC * 4);
    float*  h1      = (float*)alloc((size_t)NN * CC * 4);
    __half* h16a    = (__half*)alloc((size_t)NN * CC * 2);
    __half* h16b    = (__half*)alloc((size_t)NN * CC * 2);
    __half* hh16    = (__half*)alloc((size_t)NN * 256 * 2);
    __half* Wt      = (__half*)alloc((size_t)3 * 256 * 128 * 2);
    __half* Wet     = (__half*)alloc((size_t)128 * 64 * 2);
    float*  lsld    = (float*)alloc((size_t)NN * 4 * 4);
    int*    deg     = (int*)alloc((size_t)NN * 4);
    int4*   slab    = (int4*)alloc((size_t)NN * CAP * 16);
    float*  wd      = (float*)alloc(256);

    // 1: prep (zeros deg, Wt/Wet, wedot)
    k_prep<<<PREPN + 1, 256, 0, stream>>>(Wg, W_emb, We, att_e, Wt, Wet, wd, deg);
    // 2: slab CSR scatter
    k_scatter<<<(EE + 255) / 256, 256, 0, stream>>>(ei, ea, mu, devp, deg, slab);
    // 3: embed (MFMA, direct fp32 x)
    k_embed16<<<NN / 16, 128, 0, stream>>>(x, Wet, h0, h16a);

    float*  hc = h0;     float*  hn = h1;
    __half* hc16 = h16a; __half* hn16 = h16b;
    for (int k = 0; k < 3; ++k) {
        k_gemm16<<<NN / 16, 256, 0, stream>>>(hc16, Wt + (size_t)k * 32768,
                                              att_s + k * 256, att_d + k * 256, hh16, lsld);
        k_attn<<<NN / 8, 256, 0, stream>>>(hh16, hc, lsld, deg, slab,
                                           wd + k * 2, bg + k * 128, gw + k * 256, gb + k,
                                           hn, hn16);
        float* t1 = hc; hc = hn; hn = t1;
        __half* t2 = hc16; hc16 = hn16; hn16 = t2;
    }

    // 10: fused readout + MLP
    k_readmlp<<<GG, 128, 0, stream>>>(hc, valid, batch,
                                      fw0, fb0, fw1, fb1, fw2, fb2, fw3, fb3, out);
}